// Round 4
// baseline (151.852 us; speedup 1.0000x reference)
//
#include <hip/hip_runtime.h>
#include <cstddef>
#include <cstdint>

// Problem constants: B=2, T=2048, C=1024, H=16, hs=64
#define B_N 2
#define T_N 2048
#define C_N 1024
#define H_N 16
#define HS_N 64
#define M_N (B_N * T_N)   // 4096

typedef __attribute__((ext_vector_type(8))) short bf16x8;   // 8 bf16 = 4 VGPRs
typedef __attribute__((ext_vector_type(4))) float f32x4;
typedef __attribute__((ext_vector_type(4))) unsigned int u32x4;
typedef __attribute__((ext_vector_type(2))) unsigned int u32x2;

// 0.125 (hs^-0.5) * log2(e): folded into Wq so attention uses exp2 directly
#define QSCALE 0.18033688011112042f

__device__ __forceinline__ ushort f2bf(float f) {
    union { float f; uint32_t u; } v; v.f = f;
    uint32_t r = v.u + 0x7fffu + ((v.u >> 16) & 1u);   // round-nearest-even
    return (ushort)(r >> 16);
}
// truncating pack of two P-values (P in [0,1], rel err ~2^-9 — validated)
__device__ __forceinline__ unsigned pack2_trunc(float a, float b) {
    union { float f; uint32_t u; } x, y; x.f = a; y.f = b;
    return (x.u >> 16) | (y.u & 0xFFFF0000u);
}

// async global->LDS, 16B per lane; lds base must be wave-uniform
#define GLL16(g, l)                                                         \
    __builtin_amdgcn_global_load_lds(                                       \
        (const __attribute__((address_space(1))) unsigned int*)(g),         \
        (__attribute__((address_space(3))) unsigned int*)(l), 16, 0, 0)

// ---------------------------------------------------------------------------
// Fused fp32->bf16 convert: x | Wq(*QSCALE) | Wp | Wk | Wv (one launch).
// ---------------------------------------------------------------------------
__global__ void cvt_all_kernel(const float* __restrict__ x,
                               const float* __restrict__ Wq,
                               const float* __restrict__ Wp,
                               const float* __restrict__ Wk,
                               const float* __restrict__ Wv,
                               ushort* __restrict__ xb,
                               ushort* __restrict__ Wqb,
                               ushort* __restrict__ Wpb,
                               ushort* __restrict__ Wkvb) {
    const int S0 = M_N * C_N / 4;
    const int S1 = S0 + C_N * C_N / 4;
    const int S2 = S1 + C_N * C_N / 4;
    const int S3 = S2 + HS_N * C_N / 4;
    const int S4 = S3 + HS_N * C_N / 4;
    const int stride = gridDim.x * blockDim.x;
    for (int i = blockIdx.x * blockDim.x + threadIdx.x; i < S4; i += stride) {
        const float* src; ushort* dst; int j; float sc = 1.f;
        if (i < S0)      { src = x;  dst = xb;   j = i; }
        else if (i < S1) { src = Wq; dst = Wqb;  j = i - S0; sc = QSCALE; }
        else if (i < S2) { src = Wp; dst = Wpb;  j = i - S1; }
        else if (i < S3) { src = Wk; dst = Wkvb; j = i - S2; }
        else             { src = Wv; dst = Wkvb + HS_N * C_N; j = i - S3; }
        const float4 f = ((const float4*)src)[j];
        ushort4 o;
        o.x = f2bf(f.x * sc); o.y = f2bf(f.y * sc);
        o.z = f2bf(f.z * sc); o.w = f2bf(f.w * sc);
        ((ushort4*)dst)[j] = o;
    }
}

// ---------------------------------------------------------------------------
// bf16 MFMA GEMM — RETILED to the m97 structure: BM=128, BN=128, BK=64,
// 256 threads (4 waves 2x2, each owning a 64x64 sub-tile, acc 4x4).
// vs the old BM=64 tile: 16 ds_read_b128 / 32 MFMA per k-step (was 12/16)
// and 32KB staged per 2.1 MFLOP (was 24KB/1.0 MFLOP) — the proven
// ~874-912 TF configuration vs the ~500-600 TF half-tile.
// XCD swizzle for the 32-m-tile grid: flat%8 = XCD -> m-group; per-XCD
// footprint = x 1MB + W 2.25MB < 4MB L2. K-accumulation order unchanged
// (BK=64, same hh chain) -> bitwise-identical results to the old tile.
// MODE 0: fp32 out + bias. MODE 1: bf16 out; 9th n-tile -> kb natural +
// vbt transposed [b][d][t] (packed ushort4 = 4 consecutive t).
// ---------------------------------------------------------------------------
template <int MODE>
__global__ __launch_bounds__(256, 2) void gemm_bf16(
    const ushort* __restrict__ A,   // [M][K] bf16
    const ushort* __restrict__ W,   // [Ntot][K] bf16
    const float* __restrict__ bias, // MODE 0 only
    void* __restrict__ Cout,        // [M][1024] fp32 (MODE 0) / bf16 (MODE 1)
    ushort* __restrict__ kb,        // MODE 1: [4096][64]
    ushort* __restrict__ vbt,       // MODE 1: [2][64][2048]
    int K)
{
    __shared__ __align__(16) ushort As[128 * 64];   // 16 KB
    __shared__ __align__(16) ushort Bs[128 * 64];   // 16 KB
    // XCD swizzle (gridDim.x == 32 == M/128)
    const int flat = blockIdx.x + blockIdx.y * 32;
    const int m0 = (((flat & 7) << 2) | ((flat >> 3) & 3)) << 7;
    const int n0 = (flat >> 5) << 7;
    const int tid = threadIdx.x;
    const int wid = tid >> 6;
    const int lane = tid & 63;
    const int ln = lane & 15;
    const int quad = lane >> 4;
    const int wm = wid >> 1, wn = wid & 1;   // wave = rows wm*64+, cols wn*64+

    f32x4 acc[4][4];
    #pragma unroll
    for (int i = 0; i < 4; ++i)
        #pragma unroll
        for (int j = 0; j < 4; ++j)
            acc[i][j] = (f32x4){0.f, 0.f, 0.f, 0.f};

    const int srow = lane >> 3;          // 0..7 row within 8-row segment
    const int schk = (lane & 7) ^ srow;  // fetched chunk (row&7 == srow)

    for (int k0 = 0; k0 < K; k0 += 64) {
        __syncthreads();   // prior iteration's LDS reads complete
        #pragma unroll
        for (int t = 0; t < 4; ++t) {    // A: 16 segments of 8 rows
            const int seg = wid * 4 + t;
            GLL16(A + (size_t)(m0 + seg * 8 + srow) * K + k0 + schk * 8,
                  As + seg * 512);
        }
        #pragma unroll
        for (int t = 0; t < 4; ++t) {    // B: 16 segments of 8 rows
            const int seg = wid * 4 + t;
            GLL16(W + (size_t)(n0 + seg * 8 + srow) * K + k0 + schk * 8,
                  Bs + seg * 512);
        }
        __syncthreads();   // drains vmcnt (GLL16 counted there)

        #pragma unroll
        for (int hh = 0; hh < 2; ++hh) {
            bf16x8 af[4], bf[4];
            const int sw = ln & 7;
            #pragma unroll
            for (int i = 0; i < 4; ++i) {
                const int row = wm * 64 + i * 16 + ln;
                af[i] = *(const bf16x8*)&As[row * 64 + (((hh * 4 + quad) ^ sw) * 8)];
            }
            #pragma unroll
            for (int j = 0; j < 4; ++j) {
                const int row = wn * 64 + j * 16 + ln;
                bf[j] = *(const bf16x8*)&Bs[row * 64 + (((hh * 4 + quad) ^ sw) * 8)];
            }
            #pragma unroll
            for (int i = 0; i < 4; ++i)
                #pragma unroll
                for (int j = 0; j < 4; ++j)
                    acc[i][j] = __builtin_amdgcn_mfma_f32_16x16x32_bf16(
                        af[i], bf[j], acc[i][j], 0, 0, 0);
        }
    }

    if (MODE == 1 && n0 >= C_N) {        // kv tile: K cols 0..63, V 64..127
        #pragma unroll
        for (int i = 0; i < 4; ++i) {
            const int row0 = m0 + wm * 64 + i * 16 + quad * 4;
            #pragma unroll
            for (int j = 0; j < 4; ++j) {
                const int c2 = wn * 64 + j * 16 + ln;
                if (c2 >= 64) {
                    // vbt[b][d][t], 4 regs = 4 consecutive t
                    const int d = c2 - 64;
                    const int b = row0 >> 11;
                    const int t0 = row0 & 2047;
                    ushort4 pk;
                    pk.x = f2bf(acc[i][j][0]); pk.y = f2bf(acc[i][j][1]);
                    pk.z = f2bf(acc[i][j][2]); pk.w = f2bf(acc[i][j][3]);
                    *(ushort4*)&vbt[((size_t)b * 64 + d) * T_N + t0] = pk;
                } else {
                    #pragma unroll
                    for (int reg = 0; reg < 4; ++reg)
                        kb[(size_t)(row0 + reg) * 64 + c2] = f2bf(acc[i][j][reg]);
                }
            }
        }
        return;
    }

    #pragma unroll
    for (int i = 0; i < 4; ++i) {
        #pragma unroll
        for (int j = 0; j < 4; ++j) {
            const int col = n0 + wn * 64 + j * 16 + ln;
            const float bv = (MODE == 0) ? bias[col] : 0.f;
            #pragma unroll
            for (int reg = 0; reg < 4; ++reg) {
                const int row = m0 + wm * 64 + i * 16 + quad * 4 + reg;
                const float v = acc[i][j][reg] + bv;
                if (MODE == 0)
                    ((float*)Cout)[(size_t)row * C_N + col] = v;
                else
                    ((ushort*)Cout)[(size_t)row * C_N + col] = f2bf(v);
            }
        }
    }
}

// ---------------------------------------------------------------------------
// Flash causal MQA attention — KEY-SPLIT structure (verified round 3; FROZEN
// this round for one-variable discipline).
//
// Q uses the torch RAW-VIEW layout [B,T,C]->[B,H,T,hs]:
//   Q[b,h,t,d] = qb_flat[b*T*C + h*T*hs + t*hs + d]   (row stride hs)
//
// Structure: block = one 64-row q-tile; KVBLK=128; wave w owns keys
// [32w,32w+32).  Q entirely in registers; per wave per 128-key tile only
// 8 ds_read_b128; softmax denom associative -> per-wave partial o/l,
// ONE cross-wave LDS reduction at end; P transpose in-register via
// permlane32_swap+permlane16_swap; staging via GLL16 w=16 pre-swizzled
// global source (LDS linear); double-buffered, ONE barrier per k-tile;
// 1024 blocks (2/CU) with causal-balanced qt map.
// ---------------------------------------------------------------------------
__global__ __launch_bounds__(256, 2) void attn_mfma_kernel(
    const ushort* __restrict__ qb,
    const ushort* __restrict__ kb,    // [4096][64]
    const ushort* __restrict__ vbt,   // [2][64][2048]
    ushort* __restrict__ yb)
{
    __shared__ __align__(16) ushort smem[32768];  // 64 KB: 2 x (Ks 16KB | Vt 16KB)

    const int bh = blockIdx.x;
    const int b = bh >> 4, h = bh & 15;
    const int yy = blockIdx.y;
    // balanced qt map: resident groups (yy, yy+8, yy+16, yy+24) have ~equal work
    const int qt = (yy < 8) ? 31 - yy : (yy < 16) ? yy - 8
                 : (yy < 24) ? 39 - yy : yy - 16;
    const int nkt = (qt >> 1) + 1;    // 128-key tiles
    const int qmax = qt * 64 + 63;

    const int tid = threadIdx.x;
    const int w = tid >> 6;           // wave id = key-slice owner
    const int lane = tid & 63;
    const int ln = lane & 15;
    const int quad = lane >> 4;

    const ushort* kbase = kb + (size_t)b * T_N * HS_N;
    const ushort* vtbase = vbt + (size_t)b * HS_N * T_N;

    // ---- Q fragments, held whole loop: qf[qb4][kc2], B-operand layout
    // RAW-VIEW strip: base b*T*C + h*T*hs, row stride hs.
    bf16x8 qf[4][2];
    {
        const ushort* qs_ = qb + (size_t)b * T_N * C_N
                          + (size_t)h * T_N * HS_N
                          + (size_t)(qt * 64) * HS_N;
        #pragma unroll
        for (int q4 = 0; q4 < 4; ++q4)
            #pragma unroll
            for (int kc = 0; kc < 2; ++kc)
                qf[q4][kc] = *(const bf16x8*)(qs_ + (q4 * 16 + ln) * HS_N
                                              + kc * 32 + quad * 8);
    }

    // stage 128-key K/V tile into buf via GLL16, pre-swizzled global source.
    // K LDS slot [key][c], c = chunk-of-8 (8/row);  slot c holds global chunk c^(key&7)
    // V LDS slot [d][c],  c 0..15 (16/row);         slot c holds global chunk c^(d&15)
    auto stage = [&](int buf, int k0) {
        ushort* Ksb = smem + buf * 16384;
        ushort* Vtb = Ksb + 8192;
        #pragma unroll
        for (int i = 0; i < 4; ++i) {
            const int x = (i * 4 + w) * 64 + lane;   // flat 16B-chunk index
            const int key = x >> 3, slk = x & 7;
            GLL16(kbase + (size_t)(k0 + key) * HS_N + ((slk ^ (key & 7)) * 8),
                  Ksb + (i * 4 + w) * 512);
            const int d = x >> 4, slv = x & 15;
            GLL16(vtbase + (size_t)d * T_N + k0 + ((slv ^ (d & 15)) * 8),
                  Vtb + (i * 4 + w) * 512);
        }
    };

    f32x4 o[4][4];                    // [db][qb]  o^T[d][q] partial (this wave's keys)
    #pragma unroll
    for (int i = 0; i < 4; ++i)
        #pragma unroll
        for (int j = 0; j < 4; ++j)
            o[i][j] = (f32x4){0.f, 0.f, 0.f, 0.f};
    float lac[4] = {0.f, 0.f, 0.f, 0.f};

    stage(0, 0);

    for (int kt = 0; kt < nkt; ++kt) {
        __syncthreads();              // drains vmcnt (buf[kt&1] ready) + prior LDS reads
        if (kt + 1 < nkt) stage((kt + 1) & 1, (kt + 1) * 128);

        const int k0 = kt * 128;
        const bool dg = (kt == nkt - 1);       // only last tile crosses the diagonal
        const int kw0 = k0 + w * 32;           // this wave's first key
        if (dg && kw0 > qmax) continue;        // whole slice masked (no barrier skipped)

        const ushort* Ksb = smem + (kt & 1) * 16384;
        const ushort* Vtb = Ksb + 8192;

        // fragments: this wave's 32-key slice only
        bf16x8 kf[2][2], vf[4];
        #pragma unroll
        for (int nt = 0; nt < 2; ++nt)
            #pragma unroll
            for (int kc = 0; kc < 2; ++kc) {
                const int key = w * 32 + nt * 16 + ln;
                kf[nt][kc] = *(const bf16x8*)
                    &Ksb[key * 64 + (((kc * 4 + quad) ^ (key & 7)) * 8)];
            }
        #pragma unroll
        for (int db = 0; db < 4; ++db) {
            const int d = db * 16 + ln;
            vf[db] = *(const bf16x8*)
                &Vtb[d * 128 + (((w * 4 + quad) ^ (d & 15)) * 8)];
        }

        // QK^T: sc[nt][qb] = S^T[key = kw0+nt*16+quad*4+reg][q = qt*64+q4*16+ln]
        f32x4 sc[2][4];
        #pragma unroll
        for (int nt = 0; nt < 2; ++nt)
            #pragma unroll
            for (int q4 = 0; q4 < 4; ++q4) {
                f32x4 s = (f32x4){0.f, 0.f, 0.f, 0.f};
                s = __builtin_amdgcn_mfma_f32_16x16x32_bf16(kf[nt][0], qf[q4][0], s, 0, 0, 0);
                s = __builtin_amdgcn_mfma_f32_16x16x32_bf16(kf[nt][1], qf[q4][1], s, 0, 0, 0);
                sc[nt][q4] = s;
            }

        // softmax + pack:  pk[nt][q4][h] = bf16 pair for keys (quad*4+2h, +1)
        unsigned pk[2][4][2];
        #pragma unroll
        for (int nt = 0; nt < 2; ++nt)
            #pragma unroll
            for (int q4 = 0; q4 < 4; ++q4) {
                f32x4 s = sc[nt][q4];
                if (dg) {
                    const int qg = qt * 64 + q4 * 16 + ln;
                    #pragma unroll
                    for (int reg = 0; reg < 4; ++reg) {
                        const int key = kw0 + nt * 16 + quad * 4 + reg;
                        if (key > qg) s[reg] = -1e30f;
                    }
                }
                const float p0 = __builtin_amdgcn_exp2f(s[0]);
                const float p1 = __builtin_amdgcn_exp2f(s[1]);
                const float p2 = __builtin_amdgcn_exp2f(s[2]);
                const float p3 = __builtin_amdgcn_exp2f(s[3]);
                lac[q4] += (p0 + p1) + (p2 + p3);
                pk[nt][q4][0] = pack2_trunc(p0, p1);
                pk[nt][q4][1] = pack2_trunc(p2, p3);
            }

        // in-register transpose (D-layout -> B-operand) + PV
        #pragma unroll
        for (int q4 = 0; q4 < 4; ++q4) {
            u32x2 ab0 = __builtin_amdgcn_permlane32_swap(pk[0][q4][0], pk[1][q4][0], false, false);
            u32x2 rs0 = __builtin_amdgcn_permlane16_swap(ab0[0], ab0[1], false, false);
            u32x2 ab1 = __builtin_amdgcn_permlane32_swap(pk[0][q4][1], pk[1][q4][1], false, false);
            u32x2 rs1 = __builtin_amdgcn_permlane16_swap(ab1[0], ab1[1], false, false);
            u32x4 pw;
            pw[0] = rs0[0]; pw[1] = rs1[0]; pw[2] = rs0[1]; pw[3] = rs1[1];
            const bf16x8 pf = __builtin_bit_cast(bf16x8, pw);
            #pragma unroll
            for (int db = 0; db < 4; ++db)
                o[db][q4] = __builtin_amdgcn_mfma_f32_16x16x32_bf16(
                    vf[db], pf, o[db][q4], 0, 0, 0);
        }
    }

    // ---- epilogue: cross-wave reduce o^T and l, normalize, write y (bf16)
    // per-wave l: reduce over quads first (each lane then holds l[q=q4*16+ln])
    #pragma unroll
    for (int q4 = 0; q4 < 4; ++q4) {
        lac[q4] += __shfl_xor(lac[q4], 16);
        lac[q4] += __shfl_xor(lac[q4], 32);
    }

    float* Ored = (float*)smem;            // [4 waves][64 q][36]  (col 32 = l)
    const int qloc = 16 * w + (lane >> 2); // q-row this lane reduces
    float inv = 0.f;

    #pragma unroll
    for (int pass = 0; pass < 2; ++pass) { // d 0..31 then 32..63
        __syncthreads();                   // stage reads done / pass0 reads done
        #pragma unroll
        for (int db2 = 0; db2 < 2; ++db2)
            #pragma unroll
            for (int q4 = 0; q4 < 4; ++q4)
                *(f32x4*)&Ored[(w * 64 + q4 * 16 + ln) * 36 + db2 * 16 + quad * 4]
                    = o[pass * 2 + db2][q4];
        if (pass == 0 && quad == 0) {
            #pragma unroll
            for (int q4 = 0; q4 < 4; ++q4)
                Ored[(w * 64 + q4 * 16 + ln) * 36 + 32] = lac[q4];
        }
        __syncthreads();

        f32x4 a0 = (f32x4){0.f, 0.f, 0.f, 0.f};
        f32x4 a1 = (f32x4){0.f, 0.f, 0.f, 0.f};
        float ls = 0.f;
        #pragma unroll
        for (int v = 0; v < 4; ++v) {
            const int base = (v * 64 + qloc) * 36;
            a0 += *(const f32x4*)&Ored[base + (lane & 3) * 4];
            a1 += *(const f32x4*)&Ored[base + 16 + (lane & 3) * 4];
            if (pass == 0) ls += Ored[base + 32];
        }
        if (pass == 0) inv = 1.0f / ls;

        const int qg = qt * 64 + qloc;
        ushort* yrow = yb + ((size_t)b * T_N + qg) * C_N + h * HS_N
                       + pass * 32 + (lane & 3) * 4;
        ushort4 s0, s1;
        s0.x = f2bf(a0[0] * inv); s0.y = f2bf(a0[1] * inv);
        s0.z = f2bf(a0[2] * inv); s0.w = f2bf(a0[3] * inv);
        s1.x = f2bf(a1[0] * inv); s1.y = f2bf(a1[1] * inv);
        s1.z = f2bf(a1[2] * inv); s1.w = f2bf(a1[3] * inv);
        *(ushort4*)yrow = s0;
        *(ushort4*)(yrow + 16) = s1;
    }
}

// ---------------------------------------------------------------------------
extern "C" void kernel_launch(void* const* d_in, const int* in_sizes, int n_in,
                              void* d_out, int out_size, void* d_ws, size_t ws_size,
                              hipStream_t stream) {
    const float* x  = (const float*)d_in[0];
    const float* Wk = (const float*)d_in[1];
    const float* Wv = (const float*)d_in[2];
    const float* Wq = (const float*)d_in[3];
    const float* Wp = (const float*)d_in[4];
    const float* bp = (const float*)d_in[5];
    float* out = (float*)d_out;

    ushort* xb   = (ushort*)d_ws;                     // [4096][1024]
    ushort* qb   = xb   + (size_t)M_N * C_N;          // [4096][1024]
    ushort* yb   = qb   + (size_t)M_N * C_N;          // [4096][1024]
    ushort* kbw  = yb   + (size_t)M_N * C_N;          // [4096][64]
    ushort* vbt  = kbw  + (size_t)M_N * HS_N;         // [2][64][2048]
    ushort* Wqb  = vbt  + (size_t)B_N * HS_N * T_N;   // [1024][1024] (scaled)
    ushort* Wkvb = Wqb  + (size_t)C_N * C_N;          // [128][1024], after Wq
    ushort* Wpb  = Wkvb + (size_t)128 * C_N;          // [1024][1024]

    cvt_all_kernel<<<1024, 256, 0, stream>>>(x, Wq, Wp, Wk, Wv,
                                             xb, Wqb, Wpb, Wkvb);

    // fused q + k + v projection: W' = [Wq(scaled); Wk; Wv] (1152 rows)
    // n-tiles 0..7 -> qb; tile 8 -> kbw (natural) + vbt (transposed)
    gemm_bf16<1><<<dim3(M_N / 128, (C_N + 128) / 128), 256, 0, stream>>>(
        xb, Wqb, nullptr, qb, kbw, vbt, C_N);

    // attention -> yb bf16; key-split, 1024 blocks (one 64-row q-tile each)
    attn_mfma_kernel<<<dim3(B_N * H_N, 32), 256, 0, stream>>>(qb, kbw, vbt, yb);

    // out = y @ Wp^T + bp -> fp32
    gemm_bf16<0><<<dim3(M_N / 128, C_N / 128), 256, 0, stream>>>(
        yb, Wpb, bp, out, nullptr, nullptr, C_N);
}

// Round 6
// 142.475 us; speedup vs baseline: 1.0658x; 1.0658x over previous
//
#include <hip/hip_runtime.h>
#include <cstddef>
#include <cstdint>

// Problem constants: B=2, T=2048, C=1024, H=16, hs=64
#define B_N 2
#define T_N 2048
#define C_N 1024
#define H_N 16
#define HS_N 64
#define M_N (B_N * T_N)   // 4096

typedef __attribute__((ext_vector_type(8))) short bf16x8;   // 8 bf16 = 4 VGPRs
typedef __attribute__((ext_vector_type(4))) float f32x4;
typedef __attribute__((ext_vector_type(4))) unsigned int u32x4;
typedef __attribute__((ext_vector_type(2))) unsigned int u32x2;

// 0.125 (hs^-0.5) * log2(e): folded into Wq so attention uses exp2 directly
#define QSCALE 0.18033688011112042f

__device__ __forceinline__ ushort f2bf(float f) {
    union { float f; uint32_t u; } v; v.f = f;
    uint32_t r = v.u + 0x7fffu + ((v.u >> 16) & 1u);   // round-nearest-even
    return (ushort)(r >> 16);
}
// truncating pack of two P-values (P in [0,1], rel err ~2^-9 — validated)
__device__ __forceinline__ unsigned pack2_trunc(float a, float b) {
    union { float f; uint32_t u; } x, y; x.f = a; y.f = b;
    return (x.u >> 16) | (y.u & 0xFFFF0000u);
}

// async global->LDS, 16B per lane; lds base must be wave-uniform
#define GLL16(g, l)                                                         \
    __builtin_amdgcn_global_load_lds(                                       \
        (const __attribute__((address_space(1))) unsigned int*)(g),         \
        (__attribute__((address_space(3))) unsigned int*)(l), 16, 0, 0)

// ---------------------------------------------------------------------------
// Fused fp32->bf16 convert: x | Wq(*QSCALE) | Wp | Wk | Wv (one launch).
// ---------------------------------------------------------------------------
__global__ void cvt_all_kernel(const float* __restrict__ x,
                               const float* __restrict__ Wq,
                               const float* __restrict__ Wp,
                               const float* __restrict__ Wk,
                               const float* __restrict__ Wv,
                               ushort* __restrict__ xb,
                               ushort* __restrict__ Wqb,
                               ushort* __restrict__ Wpb,
                               ushort* __restrict__ Wkvb) {
    const int S0 = M_N * C_N / 4;
    const int S1 = S0 + C_N * C_N / 4;
    const int S2 = S1 + C_N * C_N / 4;
    const int S3 = S2 + HS_N * C_N / 4;
    const int S4 = S3 + HS_N * C_N / 4;
    const int stride = gridDim.x * blockDim.x;
    for (int i = blockIdx.x * blockDim.x + threadIdx.x; i < S4; i += stride) {
        const float* src; ushort* dst; int j; float sc = 1.f;
        if (i < S0)      { src = x;  dst = xb;   j = i; }
        else if (i < S1) { src = Wq; dst = Wqb;  j = i - S0; sc = QSCALE; }
        else if (i < S2) { src = Wp; dst = Wpb;  j = i - S1; }
        else if (i < S3) { src = Wk; dst = Wkvb; j = i - S2; }
        else             { src = Wv; dst = Wkvb + HS_N * C_N; j = i - S3; }
        const float4 f = ((const float4*)src)[j];
        ushort4 o;
        o.x = f2bf(f.x * sc); o.y = f2bf(f.y * sc);
        o.z = f2bf(f.z * sc); o.w = f2bf(f.w * sc);
        ((ushort4*)dst)[j] = o;
    }
}

// ---------------------------------------------------------------------------
// bf16 MFMA GEMM — round-3 tile: BM=64, BN=128, BK=64, 256 threads
// (4 waves 2x2, 32x64 each). The 128x128 retile (round 4) regressed +6.7us:
// at N=1024-1152 the grid was 256-288 blocks = 1 block/CU = 1 wave/SIMD,
// killing wave-level overlap. 64x128 gives 512-576 blocks (2+/CU).
// MODE 1 kv tile writes kb/vbt in MFMA FRAGMENT ORDER (see attn):
//   kfrag[key,d]  flat = ((((key>>4)*2+(d>>5))*4+((d>>3)&3))*16+(key&15))*8+(d&7)
//   vfrag[t,d]    flat = ((((t>>5)*4+(d>>4))*4+((t>>3)&3))*16+(d&15))*8+(t&7)
// so the attention kernel can load its K/V fragments as perfectly
// coalesced 16B/lane streams directly from L2 (no LDS staging).
// ---------------------------------------------------------------------------
template <int MODE>
__global__ __launch_bounds__(256, 2) void gemm_bf16(
    const ushort* __restrict__ A,   // [M][K] bf16
    const ushort* __restrict__ W,   // [Ntot][K] bf16
    const float* __restrict__ bias, // MODE 0 only
    void* __restrict__ Cout,        // [M][1024] fp32 (MODE 0) / bf16 (MODE 1)
    ushort* __restrict__ kb,        // MODE 1: kfrag order, 4096*64
    ushort* __restrict__ vbt,       // MODE 1: vfrag order, 2*64*2048
    int K)
{
    __shared__ __align__(16) ushort As[64 * 64];    // 8 KB
    __shared__ __align__(16) ushort Bs[128 * 64];   // 16 KB
    // XCD swizzle (gridDim.x == 64 == M/64)
    const int flat = blockIdx.x + (blockIdx.y << 6);
    const int m0 = (((flat & 7) << 3) | ((flat >> 3) & 7)) * 64;
    const int n0 = (flat >> 6) * 128;
    const int tid = threadIdx.x;
    const int wid = tid >> 6;
    const int lane = tid & 63;
    const int ln = lane & 15;
    const int quad = lane >> 4;
    const int wm = wid >> 1, wn = wid & 1;   // wave = rows wm*32+, cols wn*64+

    f32x4 acc[2][4];
    #pragma unroll
    for (int i = 0; i < 2; ++i)
        #pragma unroll
        for (int j = 0; j < 4; ++j)
            acc[i][j] = (f32x4){0.f, 0.f, 0.f, 0.f};

    const int srow = lane >> 3;          // 0..7 row within 8-row segment
    const int schk = (lane & 7) ^ srow;  // fetched chunk (row&7 == srow)

    for (int k0 = 0; k0 < K; k0 += 64) {
        __syncthreads();   // prior iteration's LDS reads complete
        #pragma unroll
        for (int t = 0; t < 2; ++t) {    // A: 8 segments of 8 rows
            const int seg = wid * 2 + t;
            GLL16(A + (size_t)(m0 + seg * 8 + srow) * K + k0 + schk * 8,
                  As + seg * 512);
        }
        #pragma unroll
        for (int t = 0; t < 4; ++t) {    // B: 16 segments of 8 rows
            const int seg = wid * 4 + t;
            GLL16(W + (size_t)(n0 + seg * 8 + srow) * K + k0 + schk * 8,
                  Bs + seg * 512);
        }
        __syncthreads();   // drains vmcnt (GLL16 counted there)

        #pragma unroll
        for (int hh = 0; hh < 2; ++hh) {
            bf16x8 af[2], bf[4];
            const int sw = ln & 7;
            #pragma unroll
            for (int i = 0; i < 2; ++i) {
                const int row = wm * 32 + i * 16 + ln;
                af[i] = *(const bf16x8*)&As[row * 64 + (((hh * 4 + quad) ^ sw) * 8)];
            }
            #pragma unroll
            for (int j = 0; j < 4; ++j) {
                const int row = wn * 64 + j * 16 + ln;
                bf[j] = *(const bf16x8*)&Bs[row * 64 + (((hh * 4 + quad) ^ sw) * 8)];
            }
            #pragma unroll
            for (int i = 0; i < 2; ++i)
                #pragma unroll
                for (int j = 0; j < 4; ++j)
                    acc[i][j] = __builtin_amdgcn_mfma_f32_16x16x32_bf16(
                        af[i], bf[j], acc[i][j], 0, 0, 0);
        }
    }

    if (MODE == 1 && n0 >= C_N) {        // kv tile: K cols 0..63, V 64..127
        #pragma unroll
        for (int i = 0; i < 2; ++i) {
            const int row0 = m0 + wm * 32 + i * 16 + quad * 4;
            #pragma unroll
            for (int j = 0; j < 4; ++j) {
                const int c2 = wn * 64 + j * 16 + ln;
                if (c2 >= 64) {
                    // vfrag: 4 regs = t0..t0+3 (same 8-chunk since t0%4==0)
                    const int d = c2 - 64;
                    const int b = row0 >> 11;
                    const int t0 = row0 & 2047;
                    const int flatv = ((((t0 >> 5) * 4 + (d >> 4)) * 4
                                       + ((t0 >> 3) & 3)) * 16 + (d & 15)) * 8
                                      + (t0 & 7);
                    ushort4 pk;
                    pk.x = f2bf(acc[i][j][0]); pk.y = f2bf(acc[i][j][1]);
                    pk.z = f2bf(acc[i][j][2]); pk.w = f2bf(acc[i][j][3]);
                    *(ushort4*)&vbt[(size_t)b * HS_N * T_N + flatv] = pk;
                } else {
                    #pragma unroll
                    for (int reg = 0; reg < 4; ++reg) {
                        const int key = row0 + reg;   // global 0..4095
                        kb[((((key >> 4) * 2 + (c2 >> 5)) * 4
                             + ((c2 >> 3) & 3)) * 16 + (key & 15)) * 8
                           + (c2 & 7)] = f2bf(acc[i][j][reg]);
                    }
                }
            }
        }
        return;
    }

    #pragma unroll
    for (int i = 0; i < 2; ++i) {
        #pragma unroll
        for (int j = 0; j < 4; ++j) {
            const int col = n0 + wn * 64 + j * 16 + ln;
            const float bv = (MODE == 0) ? bias[col] : 0.f;
            #pragma unroll
            for (int reg = 0; reg < 4; ++reg) {
                const int row = m0 + wm * 32 + i * 16 + quad * 4 + reg;
                const float v = acc[i][j][reg] + bv;
                if (MODE == 0)
                    ((float*)Cout)[(size_t)row * C_N + col] = v;
                else
                    ((ushort*)Cout)[(size_t)row * C_N + col] = f2bf(v);
            }
        }
    }
}

// ---------------------------------------------------------------------------
// Flash causal MQA attention — KEY-SPLIT, ZERO-STAGING (round-5 resubmit).
//
// K/V (1MB total) is fully L2-resident (4MB/XCD); staging it through LDS
// cost a full-block barrier + vmcnt-0 drain per k-tile (m97's ~20% stall)
// plus LDS round-trips — pure overhead per learn_hip m169. kb/vbt are
// PRE-SWIZZLED into MFMA fragment order by gemm1, so each wave loads its
// kf/vf fragments as coalesced 16B/lane global loads straight from L2.
// The k-loop has NO barriers, NO LDS, NO swizzle math; the 4 waves of a
// block run fully independently until the output reduction. LDS = 36KB
// epilogue buffer only.
//
// Q uses the torch RAW-VIEW layout [B,T,C]->[B,H,T,hs]:
//   Q[b,h,t,d] = qb_flat[b*T*C + h*T*hs + t*hs + d]   (row stride hs)
// ---------------------------------------------------------------------------
__global__ __launch_bounds__(256, 2) void attn_mfma_kernel(
    const ushort* __restrict__ qb,
    const ushort* __restrict__ kb,    // kfrag order
    const ushort* __restrict__ vbt,   // vfrag order
    ushort* __restrict__ yb)
{
    __shared__ __align__(16) float Ored[4 * 64 * 36];   // 36 KB epilogue only

    const int bh = blockIdx.x;
    const int b = bh >> 4, h = bh & 15;
    const int yy = blockIdx.y;
    // balanced qt map: resident groups (yy, yy+8, yy+16, yy+24) have ~equal work
    const int qt = (yy < 8) ? 31 - yy : (yy < 16) ? yy - 8
                 : (yy < 24) ? 39 - yy : yy - 16;
    const int nkt = (qt >> 1) + 1;    // 128-key tiles
    const int qmax = qt * 64 + 63;

    const int tid = threadIdx.x;
    const int w = tid >> 6;           // wave id = key-slice owner
    const int lane = tid & 63;
    const int ln = lane & 15;
    const int quad = lane >> 4;

    // ---- Q fragments, held whole loop: qf[qb4][kc2], B-operand layout
    // RAW-VIEW strip: base b*T*C + h*T*hs, row stride hs.
    bf16x8 qf[4][2];
    {
        const ushort* qs_ = qb + (size_t)b * T_N * C_N
                          + (size_t)h * T_N * HS_N
                          + (size_t)(qt * 64) * HS_N;
        #pragma unroll
        for (int q4 = 0; q4 < 4; ++q4)
            #pragma unroll
            for (int kc = 0; kc < 2; ++kc)
                qf[q4][kc] = *(const bf16x8*)(qs_ + (q4 * 16 + ln) * HS_N
                                              + kc * 32 + quad * 8);
    }

    const ushort* vbb = vbt + (size_t)b * HS_N * T_N;

    f32x4 o[4][4];                    // [db][qb]  o^T[d][q] partial (this wave's keys)
    #pragma unroll
    for (int i = 0; i < 4; ++i)
        #pragma unroll
        for (int j = 0; j < 4; ++j)
            o[i][j] = (f32x4){0.f, 0.f, 0.f, 0.f};
    float lac[4] = {0.f, 0.f, 0.f, 0.f};

    for (int kt = 0; kt < nkt; ++kt) {
        const int k0 = kt * 128;
        const bool dg = (kt == nkt - 1);       // only last tile crosses the diagonal
        const int kw0 = k0 + w * 32;           // this wave's first key
        if (dg && kw0 > qmax) break;           // whole slice masked; last tile anyway

        // fragment loads: coalesced 16B/lane, L2-resident
        const int b16 = ((b * T_N + k0) >> 4) + w * 2;   // key16 for nt=0
        bf16x8 kf[2][2], vf[4];
        #pragma unroll
        for (int nt = 0; nt < 2; ++nt)
            #pragma unroll
            for (int kc = 0; kc < 2; ++kc)
                kf[nt][kc] = *(const bf16x8*)
                    &kb[((((b16 + nt) * 2 + kc) * 4 + quad) * 16 + ln) * 8];
        const int t32 = (k0 >> 5) + w;
        #pragma unroll
        for (int db = 0; db < 4; ++db)
            vf[db] = *(const bf16x8*)
                &vbb[(((t32 * 4 + db) * 4 + quad) * 16 + ln) * 8];

        // QK^T: sc[nt][qb] = S^T[key = kw0+nt*16+quad*4+reg][q = qt*64+q4*16+ln]
        f32x4 sc[2][4];
        #pragma unroll
        for (int nt = 0; nt < 2; ++nt)
            #pragma unroll
            for (int q4 = 0; q4 < 4; ++q4) {
                f32x4 s = (f32x4){0.f, 0.f, 0.f, 0.f};
                s = __builtin_amdgcn_mfma_f32_16x16x32_bf16(kf[nt][0], qf[q4][0], s, 0, 0, 0);
                s = __builtin_amdgcn_mfma_f32_16x16x32_bf16(kf[nt][1], qf[q4][1], s, 0, 0, 0);
                sc[nt][q4] = s;
            }

        // softmax + pack:  pk[nt][q4][hf] = bf16 pair for keys (quad*4+2hf, +1)
        unsigned pk[2][4][2];
        #pragma unroll
        for (int nt = 0; nt < 2; ++nt)
            #pragma unroll
            for (int q4 = 0; q4 < 4; ++q4) {
                f32x4 s = sc[nt][q4];
                if (dg) {
                    const int qg = qt * 64 + q4 * 16 + ln;
                    #pragma unroll
                    for (int reg = 0; reg < 4; ++reg) {
                        const int key = kw0 + nt * 16 + quad * 4 + reg;
                        if (key > qg) s[reg] = -1e30f;
                    }
                }
                const float p0 = __builtin_amdgcn_exp2f(s[0]);
                const float p1 = __builtin_amdgcn_exp2f(s[1]);
                const float p2 = __builtin_amdgcn_exp2f(s[2]);
                const float p3 = __builtin_amdgcn_exp2f(s[3]);
                lac[q4] += (p0 + p1) + (p2 + p3);
                pk[nt][q4][0] = pack2_trunc(p0, p1);
                pk[nt][q4][1] = pack2_trunc(p2, p3);
            }

        // in-register transpose (D-layout -> B-operand) + PV
        #pragma unroll
        for (int q4 = 0; q4 < 4; ++q4) {
            u32x2 ab0 = __builtin_amdgcn_permlane32_swap(pk[0][q4][0], pk[1][q4][0], false, false);
            u32x2 rs0 = __builtin_amdgcn_permlane16_swap(ab0[0], ab0[1], false, false);
            u32x2 ab1 = __builtin_amdgcn_permlane32_swap(pk[0][q4][1], pk[1][q4][1], false, false);
            u32x2 rs1 = __builtin_amdgcn_permlane16_swap(ab1[0], ab1[1], false, false);
            u32x4 pw;
            pw[0] = rs0[0]; pw[1] = rs1[0]; pw[2] = rs0[1]; pw[3] = rs1[1];
            const bf16x8 pf = __builtin_bit_cast(bf16x8, pw);
            #pragma unroll
            for (int db = 0; db < 4; ++db)
                o[db][q4] = __builtin_amdgcn_mfma_f32_16x16x32_bf16(
                    vf[db], pf, o[db][q4], 0, 0, 0);
        }
    }

    // ---- epilogue: cross-wave reduce o^T and l, normalize, write y (bf16)
    // per-wave l: reduce over quads first (each lane then holds l[q=q4*16+ln])
    #pragma unroll
    for (int q4 = 0; q4 < 4; ++q4) {
        lac[q4] += __shfl_xor(lac[q4], 16);
        lac[q4] += __shfl_xor(lac[q4], 32);
    }

    const int qloc = 16 * w + (lane >> 2); // q-row this lane reduces
    float inv = 0.f;

    #pragma unroll
    for (int pass = 0; pass < 2; ++pass) { // d 0..31 then 32..63
        __syncthreads();                   // pass0 reads done (pass1) / entry
        #pragma unroll
        for (int db2 = 0; db2 < 2; ++db2)
            #pragma unroll
            for (int q4 = 0; q4 < 4; ++q4)
                *(f32x4*)&Ored[(w * 64 + q4 * 16 + ln) * 36 + db2 * 16 + quad * 4]
                    = o[pass * 2 + db2][q4];
        if (pass == 0 && quad == 0) {
            #pragma unroll
            for (int q4 = 0; q4 < 4; ++q4)
                Ored[(w * 64 + q4 * 16 + ln) * 36 + 32] = lac[q4];
        }
        __syncthreads();

        f32x4 a0 = (f32x4){0.f, 0.f, 0.f, 0.f};
        f32x4 a1 = (f32x4){0.f, 0.f, 0.f, 0.f};
        float ls = 0.f;
        #pragma unroll
        for (int v = 0; v < 4; ++v) {
            const int base = (v * 64 + qloc) * 36;
            a0 += *(const f32x4*)&Ored[base + (lane & 3) * 4];
            a1 += *(const f32x4*)&Ored[base + 16 + (lane & 3) * 4];
            if (pass == 0) ls += Ored[base + 32];
        }
        if (pass == 0) inv = 1.0f / ls;

        const int qg = qt * 64 + qloc;
        ushort* yrow = yb + ((size_t)b * T_N + qg) * C_N + h * HS_N
                       + pass * 32 + (lane & 3) * 4;
        ushort4 s0, s1;
        s0.x = f2bf(a0[0] * inv); s0.y = f2bf(a0[1] * inv);
        s0.z = f2bf(a0[2] * inv); s0.w = f2bf(a0[3] * inv);
        s1.x = f2bf(a1[0] * inv); s1.y = f2bf(a1[1] * inv);
        s1.z = f2bf(a1[2] * inv); s1.w = f2bf(a1[3] * inv);
        *(ushort4*)yrow = s0;
        *(ushort4*)(yrow + 16) = s1;
    }
}

// ---------------------------------------------------------------------------
extern "C" void kernel_launch(void* const* d_in, const int* in_sizes, int n_in,
                              void* d_out, int out_size, void* d_ws, size_t ws_size,
                              hipStream_t stream) {
    const float* x  = (const float*)d_in[0];
    const float* Wk = (const float*)d_in[1];
    const float* Wv = (const float*)d_in[2];
    const float* Wq = (const float*)d_in[3];
    const float* Wp = (const float*)d_in[4];
    const float* bp = (const float*)d_in[5];
    float* out = (float*)d_out;

    ushort* xb   = (ushort*)d_ws;                     // [4096][1024]
    ushort* qb   = xb   + (size_t)M_N * C_N;          // [4096][1024]
    ushort* yb   = qb   + (size_t)M_N * C_N;          // [4096][1024]
    ushort* kbw  = yb   + (size_t)M_N * C_N;          // kfrag, 4096*64
    ushort* vbt  = kbw  + (size_t)M_N * HS_N;         // vfrag, 2*64*2048
    ushort* Wqb  = vbt  + (size_t)B_N * HS_N * T_N;   // [1024][1024] (scaled)
    ushort* Wkvb = Wqb  + (size_t)C_N * C_N;          // [128][1024], after Wq
    ushort* Wpb  = Wkvb + (size_t)128 * C_N;          // [1024][1024]

    cvt_all_kernel<<<1024, 256, 0, stream>>>(x, Wq, Wp, Wk, Wv,
                                             xb, Wqb, Wpb, Wkvb);

    // fused q + k + v projection: W' = [Wq(scaled); Wk; Wv] (1152 rows)
    // n-tiles 0..7 -> qb; tile 8 -> kbw + vbt in fragment order
    gemm_bf16<1><<<dim3(M_N / 64, (C_N + 128) / 128), 256, 0, stream>>>(
        xb, Wqb, nullptr, qb, kbw, vbt, C_N);

    // attention -> yb bf16; key-split, zero-staging, 1024 blocks
    attn_mfma_kernel<<<dim3(B_N * H_N, 32), 256, 0, stream>>>(qb, kbw, vbt, yb);

    // out = y @ Wp^T + bp -> fp32
    gemm_bf16<0><<<dim3(M_N / 64, C_N / 128), 256, 0, stream>>>(
        yb, Wpb, bp, out, nullptr, nullptr, C_N);
}